// Round 8
// baseline (397.860 us; speedup 1.0000x reference)
//
#include <hip/hip_runtime.h>
#include <hip/hip_bf16.h>
#include <cstdint>
#include <cstddef>

typedef __bf16 bf16x8 __attribute__((ext_vector_type(8)));
typedef float floatx4 __attribute__((ext_vector_type(4)));

#define NROIS 1000
#define PD    12544   // 256*49
#define K2_1  25088   // 2*PD  (hi/lo interleaved)
#define FC_N  1024
#define K2_2  2048    // 2*1024
#define NLOC  324
#define NSC   81
#define NH    405

// ---- workspace layout (float offsets) -------------------------------------
// Liveness (per launch): fT written by prep, read by roi_pool, DEAD after.
// w1t/acc alias fT and are written only by convert_kernel (post-roi_pool).
#define OFF_FT   0u          // fT: 22,282,240 floats (89.1 MB)
#define OFF_W1T  0u          // aliases fT: 1024*25088 bf16 = 12,845,056 floats
#define OFF_ACC  12845056u   // fp32 C-accumulator: 1024*1024 floats (4 MB)
#define OFF_T2   0u
#define OFF_T3   16777216u
#define OFF_T4   20971520u
#define OFF_T5   22020096u
#define OFF_POOL 22282240u   // pooled_hl: 1024*25088 bf16 = 12,845,056 floats
#define OFF_W2T  35127296u   // 1024*2048 bf16 = 1,048,576 floats
#define OFF_WHT  36175872u   // 512*2048 bf16  =   524,288 floats
#define OFF_FC1  36700160u   // 1024*2048 bf16 = 1,048,576 floats
#define OFF_FC2  37748736u   // end = 38,797,312 floats (155.2 MB)

// ---- bf16 hi/lo helpers ----------------------------------------------------
__device__ __forceinline__ unsigned short f2bf(float x) {
    unsigned int u = __float_as_uint(x);
    u = u + 0x7fffu + ((u >> 16) & 1u);          // RNE
    return (unsigned short)(u >> 16);
}
__device__ __forceinline__ float bf2f(unsigned short h) {
    return __uint_as_float(((unsigned int)h) << 16);
}
__device__ __forceinline__ ushort2 split_hl(float f) {
    const unsigned short hi = f2bf(f);
    const unsigned short lo = f2bf(f - bf2f(hi));
    return make_ushort2(hi, lo);
}

// ---------------------------------------------------------------------------
// prep: fused transpose of all 4 pyramid levels [256][P]->[P][256] fp32.
// 1D grid 5440 = 1360 pixel-tiles x 4 channel-tiles.
// ---------------------------------------------------------------------------
__global__ __launch_bounds__(256) void prep_kernel(
    const float* __restrict__ f2, const float* __restrict__ f3,
    const float* __restrict__ f4, const float* __restrict__ f5,
    float* __restrict__ fT)
{
    __shared__ float tile[64][65];
    const int b = blockIdx.x;
    int bx = b % 1360;
    const int ctile = b / 1360;
    const float* src; float* dst; int P;
    if (bx < 1024)      {            src = f2; dst = fT + OFF_T2; P = 65536; }
    else if (bx < 1280) { bx -= 1024; src = f3; dst = fT + OFF_T3; P = 16384; }
    else if (bx < 1344) { bx -= 1280; src = f4; dst = fT + OFF_T4; P = 4096; }
    else                { bx -= 1344; src = f5; dst = fT + OFF_T5; P = 1024; }

    const int p0  = bx * 64;
    const int c0  = ctile * 64;
    const int col = threadIdx.x & 63;
    const int r0  = threadIdx.x >> 6;
#pragma unroll
    for (int r = r0; r < 64; r += 4)
        tile[r][col] = src[(size_t)(c0 + r) * P + p0 + col];
    __syncthreads();
#pragma unroll
    for (int r = r0; r < 64; r += 4)
        dst[(size_t)(p0 + r) * 256 + c0 + col] = tile[col][r];
}

// ---------------------------------------------------------------------------
// ROI align + 2x2 max: one block per (roi, ph); lane = channel.
// Output: interleaved hi/lo bf16 [roi][cell*256+c]. Reads fT (last reader).
// ---------------------------------------------------------------------------
__global__ __launch_bounds__(256) void roi_pool_kernel(
    const float* __restrict__ fT, const float* __restrict__ rois,
    const int* __restrict__ img_size, ushort2* __restrict__ pooledHL)
{
    const int b   = blockIdx.x;
    const int roi = b / 7;
    const int ph  = b - roi * 7;
    const int c   = threadIdx.x;

    const float y1 = rois[roi * 4 + 0];
    const float x1 = rois[roi * 4 + 1];
    const float y2 = rois[roi * 4 + 2];
    const float x2 = rois[roi * 4 + 3];

    const float hh = y2 - y1 + 1.0f;
    const float ww = x2 - x1 + 1.0f;
    float lvlf = floorf(logf(sqrtf(hh * ww) / 224.0f) / 0.693147f + 4.0f);
    lvlf = fminf(fmaxf(lvlf, 2.0f), 5.0f);
    const int lvl = (int)lvlf;

    const float* f;
    int H;
    if (lvl == 2)      { f = fT + OFF_T2; H = 256; }
    else if (lvl == 3) { f = fT + OFF_T3; H = 128; }
    else if (lvl == 4) { f = fT + OFF_T4; H = 64;  }
    else               { f = fT + OFF_T5; H = 32;  }
    const int W = H;

    const float imh = (float)img_size[0] - 1.0f;
    const float imw = (float)img_size[1] - 1.0f;
    const float r0 = y1 * (float)(H - 1) / imh;
    const float r1 = x1 * (float)(W - 1) / imw;
    const float r2 = y2 * (float)(H - 1) / imh;
    const float r3 = x2 * (float)(W - 1) / imw;
    const float hs  = (r2 - r0) * (1.0f / 14.0f);
    const float wst = (r3 - r1) * (1.0f / 14.0f);

    float m[7];
#pragma unroll
    for (int i = 0; i < 7; ++i) m[i] = -INFINITY;

#pragma unroll
    for (int syy = 0; syy < 2; ++syy) {
        const float cy = ((float)(ph * 2 + syy) + 0.5f) * hs + r0;
        const float fy = floorf(cy);
        int   iu  = (int)fy;
        int   idn = (int)ceilf(cy);
        const float ly = cy - fy;
        iu  = min(max(iu, 0),  H - 1);
        idn = min(max(idn, 0), H - 1);
        const float wU = 1.0f - ly, wD = ly;
        const float* rowU = f + (size_t)(iu  * W) * 256;
        const float* rowD = f + (size_t)(idn * W) * 256;

#pragma unroll
        for (int sx = 0; sx < 14; ++sx) {
            const float cx = ((float)sx + 0.5f) * wst + r1;
            const float fx = floorf(cx);
            int   il = (int)fx;
            int   ir = (int)ceilf(cx);
            const float lx = cx - fx;
            il = min(max(il, 0), W - 1);
            ir = min(max(ir, 0), W - 1);

            const float v00 = rowU[il * 256 + c];
            const float v01 = rowU[ir * 256 + c];
            const float v10 = rowD[il * 256 + c];
            const float v11 = rowD[ir * 256 + c];
            const float v = (v00 * (1.0f - lx) + v01 * lx) * wU
                          + (v10 * (1.0f - lx) + v11 * lx) * wD;
            m[sx >> 1] = fmaxf(m[sx >> 1], v);
        }
    }

    ushort2* outRow = pooledHL + (size_t)roi * PD + c;
#pragma unroll
    for (int pw = 0; pw < 7; ++pw)
        outRow[(ph * 7 + pw) * 256] = split_hl(m[pw]);
}

// ---------------------------------------------------------------------------
// convert: runs AFTER roi_pool (fT dead). One launch, 4528 blocks:
//   [0,3136):     W1 -> W1T [1024][25088] bf16 hi/lo (k-perm folded)
//   [3136,3504):  W2 -> W2T, [Wloc|Wsc] -> WhT
//   [3504,4528):  zero the 4 MB fp32 C-accumulator
// ---------------------------------------------------------------------------
__global__ __launch_bounds__(256) void convert_kernel(
    const float* __restrict__ W1, ushort2* __restrict__ W1T,
    const float* __restrict__ W2, const float* __restrict__ Wloc,
    const float* __restrict__ Wsc, ushort2* __restrict__ W2T,
    ushort2* __restrict__ WhT, float* __restrict__ acc)
{
    __shared__ float tile[64][65];
    const int b = blockIdx.x;

    if (b >= 3504) {                       // zero-acc branch
        const int i4 = (b - 3504) * 256 + threadIdx.x;   // < 262144
        *reinterpret_cast<float4*>(acc + (size_t)i4 * 4) =
            make_float4(0.f, 0.f, 0.f, 0.f);
        return;
    }

    const int col = threadIdx.x & 63;
    const int r0  = threadIdx.x >> 6;

    if (b < 3136) {
        // ---------------- convert W1 ----------------
        const int p0 = (b % 196) * 64;
        const int n0 = (b / 196) * 64;
#pragma unroll
        for (int r = r0; r < 64; r += 4) {
            const int pp   = p0 + r;
            const int ksrc = (pp & 255) * 49 + (pp >> 8);
            tile[r][col] = W1[(size_t)ksrc * 1024 + n0 + col];
        }
        __syncthreads();
#pragma unroll
        for (int nr = r0; nr < 64; nr += 4)
            W1T[(size_t)(n0 + nr) * PD + p0 + col] = split_hl(tile[col][nr]);
        return;
    }

    // ---------------- convert W2 / heads ----------------
    const int t  = b - 3136;
    const int p0 = (t % 16) * 64;
    const int gy = t / 16;                  // 0..22
    if (gy < 16) {
        const int n0 = gy * 64;
#pragma unroll
        for (int r = r0; r < 64; r += 4)
            tile[r][col] = W2[(size_t)(p0 + r) * 1024 + n0 + col];
        __syncthreads();
#pragma unroll
        for (int nr = r0; nr < 64; nr += 4)
            W2T[(size_t)(n0 + nr) * 1024 + p0 + col] = split_hl(tile[col][nr]);
    } else {
        const int n0 = (gy - 16) * 64;
#pragma unroll
        for (int r = r0; r < 64; r += 4) {
            const int pp = p0 + r;
            const int n  = n0 + col;
            float v = 0.0f;
            if (n < NLOC)    v = Wloc[(size_t)pp * NLOC + n];
            else if (n < NH) v = Wsc[(size_t)pp * NSC + (n - NLOC)];
            tile[r][col] = v;
        }
        __syncthreads();
#pragma unroll
        for (int nr = r0; nr < 64; nr += 4)
            WhT[(size_t)(n0 + nr) * 1024 + p0 + col] = split_hl(tile[col][nr]);
    }
}

// ---------------------------------------------------------------------------
// bf16 MFMA GEMM v3: 128x128 block, 4 waves (2x2), 4x4 acc of 16x16x32,
// BK=64, 32 KB LDS, XOR-swizzled chunks, global_load_lds width 16.
// grid = (splitK, N/128, M/128): blockIdx.x (k-slice) -> XCD (%8) for L2
// locality. Epilogue: fp32 atomicAdd into pre-zeroed Cacc (no partials).
// ---------------------------------------------------------------------------
__global__ __launch_bounds__(256, 3) void gemm_bf16_kernel(
    const unsigned short* __restrict__ A,
    const unsigned short* __restrict__ B,
    float* __restrict__ Cacc,
    int K2, int N, int kLen)
{
    __shared__ __align__(16) unsigned short As[128 * 64];
    __shared__ __align__(16) unsigned short Bs[128 * 64];

    const int tid  = threadIdx.x;
    const int lane = tid & 63;
    const int wave = tid >> 6;
    const int kStart = blockIdx.x * kLen;
    const int kEnd   = min(kStart + kLen, K2);
    const int n0 = blockIdx.y * 128;
    const int m0 = blockIdx.z * 128;

    const int rIn  = lane >> 3;
    const int cSrc = (lane & 7) ^ rIn;

    const int wm = wave >> 1, wn = wave & 1;
    const int mrow = lane & 15, quad = lane >> 4;

    floatx4 acc[4][4];
#pragma unroll
    for (int i = 0; i < 4; ++i)
#pragma unroll
        for (int j = 0; j < 4; ++j)
            acc[i][j] = (floatx4){0.f, 0.f, 0.f, 0.f};

    for (int k0 = kStart; k0 < kEnd; k0 += 64) {
#pragma unroll
        for (int q = 0; q < 4; ++q) {
            const int rowBase = wave * 32 + q * 8;
            const unsigned short* ga =
                A + (size_t)(m0 + rowBase + rIn) * K2 + k0 + cSrc * 8;
            const unsigned short* gb =
                B + (size_t)(n0 + rowBase + rIn) * K2 + k0 + cSrc * 8;
            __builtin_amdgcn_global_load_lds(
                (const __attribute__((address_space(1))) void*)ga,
                (__attribute__((address_space(3))) void*)&As[rowBase * 64], 16, 0, 0);
            __builtin_amdgcn_global_load_lds(
                (const __attribute__((address_space(1))) void*)gb,
                (__attribute__((address_space(3))) void*)&Bs[rowBase * 64], 16, 0, 0);
        }
        __syncthreads();

#pragma unroll
        for (int ks = 0; ks < 2; ++ks) {
            bf16x8 aF[4], bF[4];
#pragma unroll
            for (int i = 0; i < 4; ++i) {
                const int ra = wm * 64 + i * 16 + mrow;
                const int ca = ((ks * 4 + quad) ^ (ra & 7)) * 8;
                aF[i] = *reinterpret_cast<const bf16x8*>(&As[ra * 64 + ca]);
                const int rb = wn * 64 + i * 16 + mrow;
                const int cb = ((ks * 4 + quad) ^ (rb & 7)) * 8;
                bF[i] = *reinterpret_cast<const bf16x8*>(&Bs[rb * 64 + cb]);
            }
#pragma unroll
            for (int i = 0; i < 4; ++i)
#pragma unroll
                for (int j = 0; j < 4; ++j)
                    acc[i][j] = __builtin_amdgcn_mfma_f32_16x16x32_bf16(
                        aF[i], bF[j], acc[i][j], 0, 0, 0);
        }
        __syncthreads();
    }

    // C/D layout: col = lane&15, row = quad*4 + reg (m89-verified)
#pragma unroll
    for (int i = 0; i < 4; ++i) {
        const int row = m0 + wm * 64 + i * 16 + quad * 4;
#pragma unroll
        for (int j = 0; j < 4; ++j) {
            const int col = n0 + wn * 64 + j * 16 + mrow;
#pragma unroll
            for (int r = 0; r < 4; ++r)
                atomicAdd(&Cacc[(size_t)(row + r) * N + col], acc[i][j][r]);
        }
    }
}

// ---------------------------------------------------------------------------
// fc = relu(acc + bias) -> hi/lo bf16 interleaved; re-zeroes acc for the
// next GEMM. float4 path, 1024 blocks.
// ---------------------------------------------------------------------------
__global__ __launch_bounds__(256) void reduce_fc_kernel(
    float* __restrict__ acc, const float* __restrict__ bias,
    ushort2* __restrict__ outHL)
{
    const int i4 = blockIdx.x * 256 + threadIdx.x;
    const int off = i4 * 4;
    const int m = off >> 10, n = off & 1023;
    const float4 a = *reinterpret_cast<const float4*>(acc + off);
    const float4 bv = *reinterpret_cast<const float4*>(bias + n);
    ushort2* o = outHL + (size_t)m * 1024 + n;
    o[0] = split_hl(fmaxf(a.x + bv.x, 0.f));
    o[1] = split_hl(fmaxf(a.y + bv.y, 0.f));
    o[2] = split_hl(fmaxf(a.z + bv.z, 0.f));
    o[3] = split_hl(fmaxf(a.w + bv.w, 0.f));
    *reinterpret_cast<float4*>(acc + off) = make_float4(0.f, 0.f, 0.f, 0.f);
}

// heads: acc[m*512+n] + bias, split-store to out0/out1
__global__ __launch_bounds__(256) void reduce_heads_kernel(
    const float* __restrict__ acc, const float* __restrict__ bloc,
    const float* __restrict__ bsc, float* __restrict__ out0,
    float* __restrict__ out1)
{
    const int m = blockIdx.x;   // 0..999
    for (int n = threadIdx.x; n < NH; n += 256) {
        const float s = acc[(size_t)m * 512 + n];
        if (n < NLOC) out0[(size_t)m * NLOC + n] = s + bloc[n];
        else          out1[(size_t)m * NSC + (n - NLOC)] = s + bsc[n - NLOC];
    }
}

// ---------------------------------------------------------------------------
extern "C" void kernel_launch(void* const* d_in, const int* in_sizes, int n_in,
                              void* d_out, int out_size, void* d_ws, size_t ws_size,
                              hipStream_t stream)
{
    const float* f2   = (const float*)d_in[0];
    const float* f3   = (const float*)d_in[1];
    const float* f4   = (const float*)d_in[2];
    const float* f5   = (const float*)d_in[3];
    const float* rois = (const float*)d_in[4];
    const int*   img  = (const int*)d_in[5];
    const float* W1   = (const float*)d_in[6];
    const float* b1   = (const float*)d_in[7];
    const float* W2   = (const float*)d_in[8];
    const float* b2   = (const float*)d_in[9];
    const float* Wloc = (const float*)d_in[10];
    const float* bloc = (const float*)d_in[11];
    const float* Wsc  = (const float*)d_in[12];
    const float* bsc  = (const float*)d_in[13];
    float* out = (float*)d_out;

    float* ws = (float*)d_ws;
    float*   fT     = ws + OFF_FT;
    ushort2* pooled = (ushort2*)(ws + OFF_POOL);
    ushort2* w1t    = (ushort2*)(ws + OFF_W1T);     // aliases fT (dead then)
    float*   acc    = ws + OFF_ACC;                 // aliases fT (dead then)
    ushort2* w2t    = (ushort2*)(ws + OFF_W2T);
    ushort2* wht    = (ushort2*)(ws + OFF_WHT);
    ushort2* fc1    = (ushort2*)(ws + OFF_FC1);
    ushort2* fc2    = (ushort2*)(ws + OFF_FC2);

    // 1) transpose all levels (writes fT)
    prep_kernel<<<5440, 256, 0, stream>>>(f2, f3, f4, f5, fT);

    // 2) ROI pool (last reader of fT)
    roi_pool_kernel<<<7000, 256, 0, stream>>>(fT, rois, img, pooled);

    // 3) weight conversions + acc zeroing (overwrite fT region, fT now dead)
    convert_kernel<<<4528, 256, 0, stream>>>(
        W1, w1t, W2, Wloc, Wsc, w2t, wht, acc);

    // 4) fc1 = relu(pooled @ W1 + b1): grid (k=12, n=8, m=8) = 768 blocks
    gemm_bf16_kernel<<<dim3(12, 8, 8), 256, 0, stream>>>(
        (const unsigned short*)pooled, (const unsigned short*)w1t, acc,
        K2_1, 1024, 2112);                  // ceil(25088/12) rounded to 64
    reduce_fc_kernel<<<1024, 256, 0, stream>>>(acc, b1, fc1);

    // 5) fc2 = relu(fc1 @ W2 + b2): grid (k=8, n=8, m=8) = 512 blocks
    gemm_bf16_kernel<<<dim3(8, 8, 8), 256, 0, stream>>>(
        (const unsigned short*)fc1, (const unsigned short*)w2t, acc,
        K2_2, 1024, 256);
    reduce_fc_kernel<<<1024, 256, 0, stream>>>(acc, b2, fc2);

    // 6) heads: N=512 (cols 405..511 garbage, never stored)
    gemm_bf16_kernel<<<dim3(8, 4, 8), 256, 0, stream>>>(
        (const unsigned short*)fc2, (const unsigned short*)wht, acc,
        K2_2, 512, 256);
    reduce_heads_kernel<<<NROIS, 256, 0, stream>>>(
        acc, bloc, bsc, out, out + (size_t)NROIS * NLOC);
}